// Round 4
// baseline (230.941 us; speedup 1.0000x reference)
//
#include <hip/hip_runtime.h>
#include <hip/hip_bf16.h>

// Spherical: out = x * |s|  (x: 8192x4096 fp32, s: scalar fp32)
// Pure streaming scale — memory-bound, zero reuse. Nontemporal float4
// load/store; 4 float4 per thread (64 B) for memory-level parallelism.
// n = 33554432 is divisible by 16, so the uniform path has no bounds checks.

typedef float fvec4 __attribute__((ext_vector_type(4)));

__global__ __launch_bounds__(256) void spherical_scale_kernel(
    const fvec4* __restrict__ x4,
    const float* __restrict__ s_ptr,
    fvec4* __restrict__ out4,
    int n4)   // number of fvec4 elements (multiple of 4 assumed by launch)
{
    const float s = fabsf(s_ptr[0]);
    const int nthreads = gridDim.x * blockDim.x;   // = n4/4 exactly
    const int tid = blockIdx.x * blockDim.x + threadIdx.x;

    // 4 fully-coalesced strided slots: tid, tid+N, tid+2N, tid+3N.
    const int i0 = tid;
    const int i1 = tid + nthreads;
    const int i2 = tid + 2 * nthreads;
    const int i3 = tid + 3 * nthreads;

    fvec4 a = __builtin_nontemporal_load(&x4[i0]);
    fvec4 b = __builtin_nontemporal_load(&x4[i1]);
    fvec4 c = __builtin_nontemporal_load(&x4[i2]);
    fvec4 d = __builtin_nontemporal_load(&x4[i3]);
    a *= s; b *= s; c *= s; d *= s;
    __builtin_nontemporal_store(a, &out4[i0]);
    __builtin_nontemporal_store(b, &out4[i1]);
    __builtin_nontemporal_store(c, &out4[i2]);
    __builtin_nontemporal_store(d, &out4[i3]);
}

extern "C" void kernel_launch(void* const* d_in, const int* in_sizes, int n_in,
                              void* d_out, int out_size, void* d_ws, size_t ws_size,
                              hipStream_t stream) {
    const float* x = (const float*)d_in[0];
    const float* s = (const float*)d_in[1];
    float* out = (float*)d_out;

    const int n = in_sizes[0];        // 33554432 = 2^25, divisible by 16
    const int n4 = n / 4;             // 8388608 fvec4s
    const int block = 256;
    const int total_threads = n4 / 4; // 2097152, 4 fvec4 per thread
    const int grid = total_threads / block;  // 8192 blocks

    spherical_scale_kernel<<<grid, block, 0, stream>>>(
        (const fvec4*)x, s, (fvec4*)out, n4);
}